// Round 5
// baseline (415.613 us; speedup 1.0000x reference)
//
#include <hip/hip_runtime.h>
#include <hip/hip_bf16.h>
#include <cmath>

#define LRALPHA 0.2f

namespace {
constexpr int BB = 4;
constexpr int NN = 4096;
constexpr int ROWS = BB * NN;   // 16384
}

typedef __attribute__((ext_vector_type(8))) short bf16x8;
typedef __attribute__((ext_vector_type(4))) float f32x4;

static __device__ inline short f2bf(float x) {
  __hip_bfloat16 t = __float2bfloat16(x);
  return *reinterpret_cast<short*>(&t);
}
static __device__ inline float bf2f(short x) {
  __hip_bfloat16 t = *reinterpret_cast<__hip_bfloat16*>(&x);
  return __bfloat162float(t);
}

// ---------- tiny prep kernels ----------

__global__ void k_transpose_w(const float* __restrict__ W, float* __restrict__ Wt) {
  int t = blockIdx.x * 256 + threadIdx.x;      // 4096 threads total
  int k = t >> 6, c = t & 63;
  Wt[c * 64 + k] = W[k * 64 + c];
}

// h = features @ W  (wave per row, lane = out channel), plus s1 = h.a1, s2 = h.a2
__global__ void k_h(const float* __restrict__ feat, const float* __restrict__ Wt,
                    const float* __restrict__ a, float* __restrict__ h,
                    float* __restrict__ s1g, float* __restrict__ s2g) {
  int lane = threadIdx.x & 63;
  int wave = threadIdx.x >> 6;
  int row = blockIdx.x * 4 + wave;
  const float4* f4 = (const float4*)(feat + (size_t)row * 64);   // wave-uniform
  const float4* w4 = (const float4*)(Wt + (size_t)lane * 64);
  float hv = 0.f;
#pragma unroll
  for (int kk = 0; kk < 16; ++kk) {
    float4 f = f4[kk], w = w4[kk];
    hv = fmaf(f.x, w.x, hv); hv = fmaf(f.y, w.y, hv);
    hv = fmaf(f.z, w.z, hv); hv = fmaf(f.w, w.w, hv);
  }
  h[(size_t)row * 64 + lane] = hv;
  float p1 = hv * a[lane];
  float p2 = hv * a[64 + lane];
#pragma unroll
  for (int off = 32; off; off >>= 1) {
    p1 += __shfl_xor(p1, off, 64);
    p2 += __shfl_xor(p2, off, 64);
  }
  if (lane == 0) { s1g[row] = p1; s2g[row] = p2; }
}

// h (fp32 [b*N+n][c]) -> hi/lo bf16 pair, transposed: hT*[b*64+c][n]
// h = hi + lo to ~2^-18 relative (double-bf16 split for fp32-grade MFMA).
__global__ __launch_bounds__(256) void k_cvt(const float* __restrict__ h,
                                             unsigned short* __restrict__ hTh,
                                             unsigned short* __restrict__ hTl) {
  __shared__ float tile[64][65];
  int n0 = blockIdx.x * 64;     // n-tile within batch
  int b  = blockIdx.y;          // 0..3
  int c  = threadIdx.x & 63;
  int r4 = threadIdx.x >> 6;    // 0..3
#pragma unroll
  for (int rr = 0; rr < 16; ++rr) {
    int n = rr * 4 + r4;
    tile[n][c] = h[((size_t)(b * NN + n0 + n)) * 64 + c];   // coalesced
  }
  __syncthreads();
  int n  = threadIdx.x & 63;
  int c4 = threadIdx.x >> 6;
#pragma unroll
  for (int cc = 0; cc < 16; ++cc) {
    int ch = cc * 4 + c4;
    float v = tile[n][ch];
    short hi = f2bf(v);
    short lo = f2bf(v - bf2f(hi));
    size_t idx = ((size_t)(b * 64 + ch) << 12) + n0 + n;
    hTh[idx] = (unsigned short)hi;
    hTl[idx] = (unsigned short)lo;
  }
}

// per-batch max of s2 (monotone lrelu => row max of e is lrelu(s1_i + max s2))
__global__ void k_maxs2(const float* __restrict__ s2g, float* __restrict__ maxs2) {
  __shared__ float red[256];
  int b = blockIdx.x;
  float m = -1e30f;
  for (int j = threadIdx.x; j < NN; j += 256) m = fmaxf(m, s2g[b * NN + j]);
  red[threadIdx.x] = m;
  __syncthreads();
  for (int off = 128; off; off >>= 1) {
    if ((int)threadIdx.x < off) red[threadIdx.x] = fmaxf(red[threadIdx.x], red[threadIdx.x + off]);
    __syncthreads();
  }
  if (threadIdx.x == 0) maxs2[b] = red[0];
}

// Per-row: A = e^{s1-m}, A' = e^{0.2 s1 - m}, T = e^{-s1}
// Per-col: B = e^{s2}, B' = e^{0.2 s2}
// w_ij = (B_j >= T_i) ? A_i*B_j : A'_i*B'_j   (no exp, no add in hot loop)
__global__ void k_prep(const float* __restrict__ s1g, const float* __restrict__ s2g,
                       const float* __restrict__ maxs2,
                       float* __restrict__ Ag, float* __restrict__ Apg,
                       float* __restrict__ Tg,
                       float* __restrict__ Bv, float* __restrict__ Bpv) {
  int row = blockIdx.x * 256 + threadIdx.x;
  int b = row >> 12;
  float s1 = s1g[row], s2 = s2g[row];
  float t = s1 + maxs2[b];
  float m = t >= 0.f ? t : LRALPHA * t;
  Ag[row]  = expf(s1 - m);
  Apg[row] = expf(LRALPHA * s1 - m);
  Tg[row]  = expf(-s1);
  Bv[row]  = expf(s2);
  Bpv[row] = expf(LRALPHA * s2);
}

// ---------- fused attention kernel ----------
// Block: 512 threads = 8 waves; 32 rows x 64 ch per block; waves split j 8 ways
// (512 j each) for 16 waves/CU = 4/SIMD latency hiding.
// w single bf16 (what MFMA multiplies); denominator l = sum(w-hat) computed by a
// ones-B-fragment MFMA => numerator/denominator use IDENTICAL weights (error is
// deviation-weighted 2^-9). h is hi+lo bf16 pair (exact to 2^-18):
// acc += w*h_hi + w*h_lo. Two-stage LDS combine keeps LDS at ~33 KB.
__global__ __launch_bounds__(512) void k_attn(
    const unsigned short* __restrict__ hTh, const unsigned short* __restrict__ hTl,
    const float* __restrict__ Ag, const float* __restrict__ Apg,
    const float* __restrict__ Tg,
    const float* __restrict__ Bv, const float* __restrict__ Bpv,
    float* __restrict__ out) {
  __shared__ float slab[4][32][65];
  __shared__ float l_lds[4][32];

  const int wave = threadIdx.x >> 6;   // 0..7
  const int lane = threadIdx.x & 63;
  const int m = lane & 15;             // A row within subtile / D col (channel)
  const int quad = lane >> 4;
  const int row0 = blockIdx.x * 32;    // 512 blocks
  const int b = row0 >> 12;
  const int i0 = row0 + m, i1 = row0 + 16 + m;

  const float Ar0 = Ag[i0], Ap0 = Apg[i0], T0 = Tg[i0];
  const float Ar1 = Ag[i1], Ap1 = Apg[i1], T1 = Tg[i1];

  f32x4 acc00 = {0,0,0,0}, acc01 = {0,0,0,0}, acc02 = {0,0,0,0}, acc03 = {0,0,0,0};
  f32x4 acc10 = {0,0,0,0}, acc11 = {0,0,0,0}, acc12 = {0,0,0,0}, acc13 = {0,0,0,0};
  f32x4 lacc0 = {0,0,0,0}, lacc1 = {0,0,0,0};

  bf16x8 ones;
#pragma unroll
  for (int e = 0; e < 8; ++e) ones[e] = (short)0x3F80;   // bf16 1.0

  const int j0 = wave * (NN / 8) + quad * 8;         // within batch
  const float* Bq  = Bv  + (b << 12) + j0;
  const float* Bpq = Bpv + (b << 12) + j0;
  const unsigned short* hp = hTh + ((size_t)(b * 64 + m) << 12) + j0;
  const unsigned short* lp = hTl + ((size_t)(b * 64 + m) << 12) + j0;
  constexpr size_t CH16 = (size_t)16 << 12;          // 16-channel stride in hT

  for (int it = 0; it < NN / 8 / 32; ++it) {
    float4 bA = *(const float4*)(Bq);
    float4 bB = *(const float4*)(Bq + 4);
    float4 pA = *(const float4*)(Bpq);
    float4 pB = *(const float4*)(Bpq + 4);
    float bvv[8] = {bA.x, bA.y, bA.z, bA.w, bB.x, bB.y, bB.z, bB.w};
    float pvv[8] = {pA.x, pA.y, pA.z, pA.w, pB.x, pB.y, pB.z, pB.w};

    bf16x8 af0, af1;
#pragma unroll
    for (int e = 0; e < 8; ++e) {
      float Bj = bvv[e], Bpj = pvv[e];
      float w0 = (Bj >= T0) ? (Ar0 * Bj) : (Ap0 * Bpj);
      float w1 = (Bj >= T1) ? (Ar1 * Bj) : (Ap1 * Bpj);
      af0[e] = f2bf(w0);
      af1[e] = f2bf(w1);
    }

    bf16x8 hh0 = *(const bf16x8*)(hp);
    bf16x8 hh1 = *(const bf16x8*)(hp + CH16);
    bf16x8 hh2 = *(const bf16x8*)(hp + 2 * CH16);
    bf16x8 hh3 = *(const bf16x8*)(hp + 3 * CH16);
    bf16x8 hl0 = *(const bf16x8*)(lp);
    bf16x8 hl1 = *(const bf16x8*)(lp + CH16);
    bf16x8 hl2 = *(const bf16x8*)(lp + 2 * CH16);
    bf16x8 hl3 = *(const bf16x8*)(lp + 3 * CH16);

    lacc0 = __builtin_amdgcn_mfma_f32_16x16x32_bf16(af0, ones, lacc0, 0, 0, 0);
    lacc1 = __builtin_amdgcn_mfma_f32_16x16x32_bf16(af1, ones, lacc1, 0, 0, 0);
    acc00 = __builtin_amdgcn_mfma_f32_16x16x32_bf16(af0, hh0, acc00, 0, 0, 0);
    acc00 = __builtin_amdgcn_mfma_f32_16x16x32_bf16(af0, hl0, acc00, 0, 0, 0);
    acc01 = __builtin_amdgcn_mfma_f32_16x16x32_bf16(af0, hh1, acc01, 0, 0, 0);
    acc01 = __builtin_amdgcn_mfma_f32_16x16x32_bf16(af0, hl1, acc01, 0, 0, 0);
    acc02 = __builtin_amdgcn_mfma_f32_16x16x32_bf16(af0, hh2, acc02, 0, 0, 0);
    acc02 = __builtin_amdgcn_mfma_f32_16x16x32_bf16(af0, hl2, acc02, 0, 0, 0);
    acc03 = __builtin_amdgcn_mfma_f32_16x16x32_bf16(af0, hh3, acc03, 0, 0, 0);
    acc03 = __builtin_amdgcn_mfma_f32_16x16x32_bf16(af0, hl3, acc03, 0, 0, 0);
    acc10 = __builtin_amdgcn_mfma_f32_16x16x32_bf16(af1, hh0, acc10, 0, 0, 0);
    acc10 = __builtin_amdgcn_mfma_f32_16x16x32_bf16(af1, hl0, acc10, 0, 0, 0);
    acc11 = __builtin_amdgcn_mfma_f32_16x16x32_bf16(af1, hh1, acc11, 0, 0, 0);
    acc11 = __builtin_amdgcn_mfma_f32_16x16x32_bf16(af1, hl1, acc11, 0, 0, 0);
    acc12 = __builtin_amdgcn_mfma_f32_16x16x32_bf16(af1, hh2, acc12, 0, 0, 0);
    acc12 = __builtin_amdgcn_mfma_f32_16x16x32_bf16(af1, hl2, acc12, 0, 0, 0);
    acc13 = __builtin_amdgcn_mfma_f32_16x16x32_bf16(af1, hh3, acc13, 0, 0, 0);
    acc13 = __builtin_amdgcn_mfma_f32_16x16x32_bf16(af1, hl3, acc13, 0, 0, 0);

    Bq += 32; Bpq += 32; hp += 32; lp += 32;
  }

  // two-stage cross-wave combine (waves 0-3 write, then waves 4-7 add)
  const int sidx = wave & 3;
  if (wave < 4) {
#pragma unroll
    for (int reg = 0; reg < 4; ++reg) {
      int rl = quad * 4 + reg;
      slab[sidx][rl][m]      = acc00[reg];
      slab[sidx][rl][m + 16] = acc01[reg];
      slab[sidx][rl][m + 32] = acc02[reg];
      slab[sidx][rl][m + 48] = acc03[reg];
      slab[sidx][16 + rl][m]      = acc10[reg];
      slab[sidx][16 + rl][m + 16] = acc11[reg];
      slab[sidx][16 + rl][m + 32] = acc12[reg];
      slab[sidx][16 + rl][m + 48] = acc13[reg];
    }
    if (m == 0) {
#pragma unroll
      for (int reg = 0; reg < 4; ++reg) {
        l_lds[sidx][quad * 4 + reg]      = lacc0[reg];
        l_lds[sidx][16 + quad * 4 + reg] = lacc1[reg];
      }
    }
  }
  __syncthreads();
  if (wave >= 4) {
#pragma unroll
    for (int reg = 0; reg < 4; ++reg) {
      int rl = quad * 4 + reg;
      slab[sidx][rl][m]      += acc00[reg];
      slab[sidx][rl][m + 16] += acc01[reg];
      slab[sidx][rl][m + 32] += acc02[reg];
      slab[sidx][rl][m + 48] += acc03[reg];
      slab[sidx][16 + rl][m]      += acc10[reg];
      slab[sidx][16 + rl][m + 16] += acc11[reg];
      slab[sidx][16 + rl][m + 32] += acc12[reg];
      slab[sidx][16 + rl][m + 48] += acc13[reg];
    }
    if (m == 0) {
#pragma unroll
      for (int reg = 0; reg < 4; ++reg) {
        l_lds[sidx][quad * 4 + reg]      += lacc0[reg];
        l_lds[sidx][16 + quad * 4 + reg] += lacc1[reg];
      }
    }
  }
  __syncthreads();

  // combine + normalize + store (each thread: 4 output elements)
#pragma unroll
  for (int k = 0; k < 4; ++k) {
    int f = threadIdx.x + 512 * k;      // 0..2047
    int rl = f >> 6, c = f & 63;
    float s = slab[0][rl][c] + slab[1][rl][c] + slab[2][rl][c] + slab[3][rl][c];
    float L = l_lds[0][rl] + l_lds[1][rl] + l_lds[2][rl] + l_lds[3][rl];
    out[((size_t)(row0 + rl)) * 64 + c] = s / L;
  }
}

// ---------- launcher ----------

extern "C" void kernel_launch(void* const* d_in, const int* in_sizes, int n_in,
                              void* d_out, int out_size, void* d_ws, size_t ws_size,
                              hipStream_t stream) {
  const float* feat = (const float*)d_in[0];
  // d_in[1] = adj : UNUSED by the reference computation
  const float* W = (const float*)d_in[2];
  const float* a = (const float*)d_in[3];
  float* out = (float*)d_out;

  char* ws = (char*)d_ws;
  size_t off = 0;
  auto carve = [&](size_t bytes) -> char* {
    char* p = ws + off;
    off = (off + bytes + 255) & ~(size_t)255;
    return p;
  };
  float*          h   = (float*)carve((size_t)ROWS * 64 * sizeof(float));          // 4 MB
  unsigned short* hTh = (unsigned short*)carve((size_t)ROWS * 64 * sizeof(unsigned short)); // 2 MB
  unsigned short* hTl = (unsigned short*)carve((size_t)ROWS * 64 * sizeof(unsigned short)); // 2 MB
  float* Wt    = (float*)carve(64 * 64 * sizeof(float));
  float* s1g   = (float*)carve(ROWS * sizeof(float));
  float* s2g   = (float*)carve(ROWS * sizeof(float));
  float* Ag    = (float*)carve(ROWS * sizeof(float));
  float* Apg   = (float*)carve(ROWS * sizeof(float));
  float* Tg    = (float*)carve(ROWS * sizeof(float));
  float* Bv    = (float*)carve(ROWS * sizeof(float));
  float* Bpv   = (float*)carve(ROWS * sizeof(float));
  float* maxs2 = (float*)carve(16 * sizeof(float));

  k_transpose_w<<<16, 256, 0, stream>>>(W, Wt);
  k_h<<<ROWS / 4, 256, 0, stream>>>(feat, Wt, a, h, s1g, s2g);
  k_cvt<<<dim3(NN / 64, BB), 256, 0, stream>>>(h, hTh, hTl);
  k_maxs2<<<BB, 256, 0, stream>>>(s2g, maxs2);
  k_prep<<<ROWS / 256, 256, 0, stream>>>(s1g, s2g, maxs2, Ag, Apg, Tg, Bv, Bpv);
  k_attn<<<ROWS / 32, 512, 0, stream>>>(hTh, hTl, Ag, Apg, Tg, Bv, Bpv, out);
}

// Round 6
// 395.571 us; speedup vs baseline: 1.0507x; 1.0507x over previous
//
#include <hip/hip_runtime.h>
#include <hip/hip_bf16.h>
#include <cmath>

#define LRALPHA 0.2f

namespace {
constexpr int BB = 4;
constexpr int NN = 4096;
constexpr int ROWS = BB * NN;   // 16384
}

typedef __attribute__((ext_vector_type(8))) short bf16x8;
typedef __attribute__((ext_vector_type(4))) float f32x4;

static __device__ inline short f2bf(float x) {
  __hip_bfloat16 t = __float2bfloat16(x);
  return *reinterpret_cast<short*>(&t);
}
static __device__ inline float bf2f(short x) {
  __hip_bfloat16 t = *reinterpret_cast<__hip_bfloat16*>(&x);
  return __bfloat162float(t);
}
// packed RNE fp32->bf16 for two POSITIVE FINITE values (no NaN guard needed):
// elem0 = low 16 bits, elem1 = high 16 bits (little-endian pair in one dword)
static __device__ inline unsigned int packRNE(float a, float b) {
  unsigned int ua = __float_as_uint(a), ub = __float_as_uint(b);
  unsigned int ra = ua + 0x7FFFu + ((ua >> 16) & 1u);
  unsigned int rb = ub + 0x7FFFu + ((ub >> 16) & 1u);
  return (ra >> 16) | (rb & 0xFFFF0000u);
}

// ---------- fused h kernel ----------
// 64 rows/block, 256 threads. Lane caches W[:,lane] in 64 VGPRs (reused for 16
// rows). h staged in LDS, then hi/lo bf16 transposed store (hT*[b*64+c][n]),
// plus s1 = h.a1, s2 = h.a2 per row.
__global__ __launch_bounds__(256) void k_hcvt(
    const float* __restrict__ feat, const float* __restrict__ W,
    const float* __restrict__ a,
    unsigned short* __restrict__ hTh, unsigned short* __restrict__ hTl,
    float* __restrict__ s1g, float* __restrict__ s2g) {
  __shared__ float tile[64][65];
  const int lane = threadIdx.x & 63;
  const int wave = threadIdx.x >> 6;
  const int row0 = blockIdx.x * 64;    // 256 blocks; never straddles a batch

  float wreg[64];
#pragma unroll
  for (int k = 0; k < 64; ++k) wreg[k] = W[k * 64 + lane];  // coalesced, once
  const float a1 = a[lane], a2 = a[64 + lane];

  for (int r = 0; r < 16; ++r) {
    const int row = row0 + wave * 16 + r;
    const float4* f4 = (const float4*)(feat + (size_t)row * 64);  // wave-uniform
    float hv = 0.f;
#pragma unroll
    for (int kk = 0; kk < 16; ++kk) {
      float4 f = f4[kk];
      hv = fmaf(f.x, wreg[4 * kk + 0], hv);
      hv = fmaf(f.y, wreg[4 * kk + 1], hv);
      hv = fmaf(f.z, wreg[4 * kk + 2], hv);
      hv = fmaf(f.w, wreg[4 * kk + 3], hv);
    }
    tile[wave * 16 + r][lane] = hv;
    float p1 = hv * a1, p2 = hv * a2;
#pragma unroll
    for (int off = 32; off; off >>= 1) {
      p1 += __shfl_xor(p1, off, 64);
      p2 += __shfl_xor(p2, off, 64);
    }
    if (lane == 0) { s1g[row] = p1; s2g[row] = p2; }
  }
  __syncthreads();

  // cvt + transposed store: lane = n within tile, wave picks channel subset
  const int b = row0 >> 12;
  const int n0 = row0 & (NN - 1);
#pragma unroll
  for (int cc = 0; cc < 16; ++cc) {
    int ch = cc * 4 + wave;
    float v = tile[lane][ch];          // stride 65: 2-way bank alias (free)
    short hi = f2bf(v);
    short lo = f2bf(v - bf2f(hi));     // h = hi + lo to ~2^-18
    size_t idx = ((size_t)(b * 64 + ch) << 12) + n0 + lane;
    hTh[idx] = (unsigned short)hi;
    hTl[idx] = (unsigned short)lo;
  }
}

// per-batch max of s2 (monotone lrelu => row max of e is lrelu(s1_i + max s2))
__global__ void k_maxs2(const float* __restrict__ s2g, float* __restrict__ maxs2) {
  __shared__ float red[256];
  int b = blockIdx.x;
  float m = -1e30f;
  for (int j = threadIdx.x; j < NN; j += 256) m = fmaxf(m, s2g[b * NN + j]);
  red[threadIdx.x] = m;
  __syncthreads();
  for (int off = 128; off; off >>= 1) {
    if ((int)threadIdx.x < off) red[threadIdx.x] = fmaxf(red[threadIdx.x], red[threadIdx.x + off]);
    __syncthreads();
  }
  if (threadIdx.x == 0) maxs2[b] = red[0];
}

// Per-row: A = e^{s1-m}, A' = e^{0.2 s1 - m}, T = e^{-s1}
// Per-col: B = e^{s2}, B' = e^{0.2 s2}
// w_ij = (B_j >= T_i) ? A_i*B_j : A'_i*B'_j   (no exp, no add in hot loop)
__global__ void k_prep(const float* __restrict__ s1g, const float* __restrict__ s2g,
                       const float* __restrict__ maxs2,
                       float* __restrict__ Ag, float* __restrict__ Apg,
                       float* __restrict__ Tg,
                       float* __restrict__ Bv, float* __restrict__ Bpv) {
  int row = blockIdx.x * 256 + threadIdx.x;
  int b = row >> 12;
  float s1 = s1g[row], s2 = s2g[row];
  float t = s1 + maxs2[b];
  float m = t >= 0.f ? t : LRALPHA * t;
  Ag[row]  = expf(s1 - m);
  Apg[row] = expf(LRALPHA * s1 - m);
  Tg[row]  = expf(-s1);
  Bv[row]  = expf(s2);
  Bpv[row] = expf(LRALPHA * s2);
}

// ---------- fused attention kernel ----------
// Block: 512 threads = 8 waves; 32 rows x 64 ch; waves split j 8 ways.
// __launch_bounds__(512, 4): cap VGPR at 128 -> guaranteed 4 waves/SIMD
// (round-5 lesson: without the cap, >128 VGPR pinned us at 2 waves/SIMD).
// w single bf16; denominator via ones-B MFMA (identical weights numerator/
// denominator); h hi+lo bf16 pair (exact to 2^-18).
__global__ __launch_bounds__(512, 4) void k_attn(
    const unsigned short* __restrict__ hTh, const unsigned short* __restrict__ hTl,
    const float* __restrict__ Ag, const float* __restrict__ Apg,
    const float* __restrict__ Tg,
    const float* __restrict__ Bv, const float* __restrict__ Bpv,
    float* __restrict__ out) {
  __shared__ float slab[4][32][65];
  __shared__ float l_lds[4][32];

  const int wave = threadIdx.x >> 6;   // 0..7
  const int lane = threadIdx.x & 63;
  const int m = lane & 15;             // A row within subtile / D col (channel)
  const int quad = lane >> 4;
  const int row0 = blockIdx.x * 32;    // 512 blocks
  const int b = row0 >> 12;
  const int i0 = row0 + m, i1 = row0 + 16 + m;

  const float Ar0 = Ag[i0], Ap0 = Apg[i0], T0 = Tg[i0];
  const float Ar1 = Ag[i1], Ap1 = Apg[i1], T1 = Tg[i1];

  f32x4 acc00 = {0,0,0,0}, acc01 = {0,0,0,0}, acc02 = {0,0,0,0}, acc03 = {0,0,0,0};
  f32x4 acc10 = {0,0,0,0}, acc11 = {0,0,0,0}, acc12 = {0,0,0,0}, acc13 = {0,0,0,0};
  f32x4 lacc0 = {0,0,0,0}, lacc1 = {0,0,0,0};

  bf16x8 ones;
#pragma unroll
  for (int e = 0; e < 8; ++e) ones[e] = (short)0x3F80;   // bf16 1.0

  const int j0 = wave * (NN / 8) + quad * 8;         // within batch
  const float* Bq  = Bv  + (b << 12) + j0;
  const float* Bpq = Bpv + (b << 12) + j0;
  const unsigned short* hp = hTh + ((size_t)(b * 64 + m) << 12) + j0;
  const unsigned short* lp = hTl + ((size_t)(b * 64 + m) << 12) + j0;
  constexpr size_t CH16 = (size_t)16 << 12;          // 16-channel stride in hT

  for (int it = 0; it < NN / 8 / 32; ++it) {
    float4 bA = *(const float4*)(Bq);
    float4 bB = *(const float4*)(Bq + 4);
    float4 pA = *(const float4*)(Bpq);
    float4 pB = *(const float4*)(Bpq + 4);
    float bvv[8] = {bA.x, bA.y, bA.z, bA.w, bB.x, bB.y, bB.z, bB.w};
    float pvv[8] = {pA.x, pA.y, pA.z, pA.w, pB.x, pB.y, pB.z, pB.w};

    float w0v[8], w1v[8];
#pragma unroll
    for (int e = 0; e < 8; ++e) {
      float Bj = bvv[e], Bpj = pvv[e];
      w0v[e] = (Bj >= T0) ? (Ar0 * Bj) : (Ap0 * Bpj);
      w1v[e] = (Bj >= T1) ? (Ar1 * Bj) : (Ap1 * Bpj);
    }
    union { bf16x8 v; unsigned int u[4]; } af0u, af1u;
#pragma unroll
    for (int p = 0; p < 4; ++p) {
      af0u.u[p] = packRNE(w0v[2 * p], w0v[2 * p + 1]);
      af1u.u[p] = packRNE(w1v[2 * p], w1v[2 * p + 1]);
    }
    bf16x8 af0 = af0u.v, af1 = af1u.v;

    bf16x8 hh0 = *(const bf16x8*)(hp);
    bf16x8 hh1 = *(const bf16x8*)(hp + CH16);
    bf16x8 hh2 = *(const bf16x8*)(hp + 2 * CH16);
    bf16x8 hh3 = *(const bf16x8*)(hp + 3 * CH16);
    bf16x8 hl0 = *(const bf16x8*)(lp);
    bf16x8 hl1 = *(const bf16x8*)(lp + CH16);
    bf16x8 hl2 = *(const bf16x8*)(lp + 2 * CH16);
    bf16x8 hl3 = *(const bf16x8*)(lp + 3 * CH16);

    lacc0 = __builtin_amdgcn_mfma_f32_16x16x32_bf16(af0, ones, lacc0, 0, 0, 0);
    lacc1 = __builtin_amdgcn_mfma_f32_16x16x32_bf16(af1, ones, lacc1, 0, 0, 0);
    acc00 = __builtin_amdgcn_mfma_f32_16x16x32_bf16(af0, hh0, acc00, 0, 0, 0);
    acc00 = __builtin_amdgcn_mfma_f32_16x16x32_bf16(af0, hl0, acc00, 0, 0, 0);
    acc01 = __builtin_amdgcn_mfma_f32_16x16x32_bf16(af0, hh1, acc01, 0, 0, 0);
    acc01 = __builtin_amdgcn_mfma_f32_16x16x32_bf16(af0, hl1, acc01, 0, 0, 0);
    acc02 = __builtin_amdgcn_mfma_f32_16x16x32_bf16(af0, hh2, acc02, 0, 0, 0);
    acc02 = __builtin_amdgcn_mfma_f32_16x16x32_bf16(af0, hl2, acc02, 0, 0, 0);
    acc03 = __builtin_amdgcn_mfma_f32_16x16x32_bf16(af0, hh3, acc03, 0, 0, 0);
    acc03 = __builtin_amdgcn_mfma_f32_16x16x32_bf16(af0, hl3, acc03, 0, 0, 0);
    acc10 = __builtin_amdgcn_mfma_f32_16x16x32_bf16(af1, hh0, acc10, 0, 0, 0);
    acc10 = __builtin_amdgcn_mfma_f32_16x16x32_bf16(af1, hl0, acc10, 0, 0, 0);
    acc11 = __builtin_amdgcn_mfma_f32_16x16x32_bf16(af1, hh1, acc11, 0, 0, 0);
    acc11 = __builtin_amdgcn_mfma_f32_16x16x32_bf16(af1, hl1, acc11, 0, 0, 0);
    acc12 = __builtin_amdgcn_mfma_f32_16x16x32_bf16(af1, hh2, acc12, 0, 0, 0);
    acc12 = __builtin_amdgcn_mfma_f32_16x16x32_bf16(af1, hl2, acc12, 0, 0, 0);
    acc13 = __builtin_amdgcn_mfma_f32_16x16x32_bf16(af1, hh3, acc13, 0, 0, 0);
    acc13 = __builtin_amdgcn_mfma_f32_16x16x32_bf16(af1, hl3, acc13, 0, 0, 0);

    Bq += 32; Bpq += 32; hp += 32; lp += 32;
  }

  // two-stage cross-wave combine (waves 0-3 write, then waves 4-7 add)
  const int sidx = wave & 3;
  if (wave < 4) {
#pragma unroll
    for (int reg = 0; reg < 4; ++reg) {
      int rl = quad * 4 + reg;
      slab[sidx][rl][m]      = acc00[reg];
      slab[sidx][rl][m + 16] = acc01[reg];
      slab[sidx][rl][m + 32] = acc02[reg];
      slab[sidx][rl][m + 48] = acc03[reg];
      slab[sidx][16 + rl][m]      = acc10[reg];
      slab[sidx][16 + rl][m + 16] = acc11[reg];
      slab[sidx][16 + rl][m + 32] = acc12[reg];
      slab[sidx][16 + rl][m + 48] = acc13[reg];
    }
    if (m == 0) {
#pragma unroll
      for (int reg = 0; reg < 4; ++reg) {
        l_lds[sidx][quad * 4 + reg]      = lacc0[reg];
        l_lds[sidx][16 + quad * 4 + reg] = lacc1[reg];
      }
    }
  }
  __syncthreads();
  if (wave >= 4) {
#pragma unroll
    for (int reg = 0; reg < 4; ++reg) {
      int rl = quad * 4 + reg;
      slab[sidx][rl][m]      += acc00[reg];
      slab[sidx][rl][m + 16] += acc01[reg];
      slab[sidx][rl][m + 32] += acc02[reg];
      slab[sidx][rl][m + 48] += acc03[reg];
      slab[sidx][16 + rl][m]      += acc10[reg];
      slab[sidx][16 + rl][m + 16] += acc11[reg];
      slab[sidx][16 + rl][m + 32] += acc12[reg];
      slab[sidx][16 + rl][m + 48] += acc13[reg];
    }
    if (m == 0) {
#pragma unroll
      for (int reg = 0; reg < 4; ++reg) {
        l_lds[sidx][quad * 4 + reg]      += lacc0[reg];
        l_lds[sidx][16 + quad * 4 + reg] += lacc1[reg];
      }
    }
  }
  __syncthreads();

  // combine + normalize + store (each thread: 4 output elements)
#pragma unroll
  for (int k = 0; k < 4; ++k) {
    int f = threadIdx.x + 512 * k;      // 0..2047
    int rl = f >> 6, c = f & 63;
    float s = slab[0][rl][c] + slab[1][rl][c] + slab[2][rl][c] + slab[3][rl][c];
    float L = l_lds[0][rl] + l_lds[1][rl] + l_lds[2][rl] + l_lds[3][rl];
    out[((size_t)(row0 + rl)) * 64 + c] = s / L;
  }
}

// ---------- launcher ----------

extern "C" void kernel_launch(void* const* d_in, const int* in_sizes, int n_in,
                              void* d_out, int out_size, void* d_ws, size_t ws_size,
                              hipStream_t stream) {
  const float* feat = (const float*)d_in[0];
  // d_in[1] = adj : UNUSED by the reference computation
  const float* W = (const float*)d_in[2];
  const float* a = (const float*)d_in[3];
  float* out = (float*)d_out;

  char* ws = (char*)d_ws;
  size_t off = 0;
  auto carve = [&](size_t bytes) -> char* {
    char* p = ws + off;
    off = (off + bytes + 255) & ~(size_t)255;
    return p;
  };
  unsigned short* hTh = (unsigned short*)carve((size_t)ROWS * 64 * sizeof(unsigned short)); // 2 MB
  unsigned short* hTl = (unsigned short*)carve((size_t)ROWS * 64 * sizeof(unsigned short)); // 2 MB
  float* s1g   = (float*)carve(ROWS * sizeof(float));
  float* s2g   = (float*)carve(ROWS * sizeof(float));
  float* Ag    = (float*)carve(ROWS * sizeof(float));
  float* Apg   = (float*)carve(ROWS * sizeof(float));
  float* Tg    = (float*)carve(ROWS * sizeof(float));
  float* Bv    = (float*)carve(ROWS * sizeof(float));
  float* Bpv   = (float*)carve(ROWS * sizeof(float));
  float* maxs2 = (float*)carve(16 * sizeof(float));

  k_hcvt<<<ROWS / 64, 256, 0, stream>>>(feat, W, a, hTh, hTl, s1g, s2g);
  k_maxs2<<<BB, 256, 0, stream>>>(s2g, maxs2);
  k_prep<<<ROWS / 256, 256, 0, stream>>>(s1g, s2g, maxs2, Ag, Apg, Tg, Bv, Bpv);
  k_attn<<<ROWS / 32, 512, 0, stream>>>(hTh, hTl, Ag, Apg, Tg, Bv, Bpv, out);
}

// Round 7
// 391.122 us; speedup vs baseline: 1.0626x; 1.0114x over previous
//
#include <hip/hip_runtime.h>
#include <hip/hip_bf16.h>
#include <cmath>

#define LRALPHA 0.2f

namespace {
constexpr int BB = 4;
constexpr int NN = 4096;
constexpr int ROWS = BB * NN;   // 16384
}

typedef __attribute__((ext_vector_type(8))) short bf16x8;
typedef __attribute__((ext_vector_type(4))) float f32x4;

static __device__ inline short f2bf(float x) {
  __hip_bfloat16 t = __float2bfloat16(x);
  return *reinterpret_cast<short*>(&t);
}
static __device__ inline float bf2f(short x) {
  __hip_bfloat16 t = *reinterpret_cast<__hip_bfloat16*>(&x);
  return __bfloat162float(t);
}
// packed RNE fp32->bf16 for two POSITIVE FINITE values (no NaN guard needed):
// elem0 = low 16 bits, elem1 = high 16 bits
static __device__ inline unsigned int packRNE(float a, float b) {
  unsigned int ua = __float_as_uint(a), ub = __float_as_uint(b);
  unsigned int ra = ua + 0x7FFFu + ((ua >> 16) & 1u);
  unsigned int rb = ub + 0x7FFFu + ((ub >> 16) & 1u);
  return (ra >> 16) | (rb & 0xFFFF0000u);
}

// ---------- fused h + prep kernel ----------
// 64 rows/block, 256 threads. Lane caches W[:,lane] in 64 VGPRs. h staged in
// LDS -> hi/lo bf16 transposed store (hT*[b*64+c][n]). Per row computes
// s1 = h.a1, s2 = h.a2 and directly the exp-precomputes (NO max-shift: s1,s2
// are unit-variance, exp() <= ~150, all sums safely in fp32; the shift cancels
// in numerator/denominator so dropping it is exact in the ratio):
//   A = e^{s1}, A' = e^{0.2 s1}, T = e^{-s1}, B = e^{s2}, B' = e^{0.2 s2}
// Hot-loop weight: w_ij = (B_j >= T_i) ? A_i*B_j : A'_i*B'_j
__global__ __launch_bounds__(256) void k_hcvt(
    const float* __restrict__ feat, const float* __restrict__ W,
    const float* __restrict__ a,
    unsigned short* __restrict__ hTh, unsigned short* __restrict__ hTl,
    float* __restrict__ Ag, float* __restrict__ Apg, float* __restrict__ Tg,
    float* __restrict__ Bv, float* __restrict__ Bpv) {
  __shared__ float tile[64][65];
  const int lane = threadIdx.x & 63;
  const int wave = threadIdx.x >> 6;
  const int row0 = blockIdx.x * 64;    // 256 blocks; never straddles a batch

  float wreg[64];
#pragma unroll
  for (int k = 0; k < 64; ++k) wreg[k] = W[k * 64 + lane];  // coalesced, once
  const float a1 = a[lane], a2 = a[64 + lane];

  for (int r = 0; r < 16; ++r) {
    const int row = row0 + wave * 16 + r;
    const float4* f4 = (const float4*)(feat + (size_t)row * 64);  // wave-uniform
    float hv = 0.f;
#pragma unroll
    for (int kk = 0; kk < 16; ++kk) {
      float4 f = f4[kk];
      hv = fmaf(f.x, wreg[4 * kk + 0], hv);
      hv = fmaf(f.y, wreg[4 * kk + 1], hv);
      hv = fmaf(f.z, wreg[4 * kk + 2], hv);
      hv = fmaf(f.w, wreg[4 * kk + 3], hv);
    }
    tile[wave * 16 + r][lane] = hv;
    float p1 = hv * a1, p2 = hv * a2;
#pragma unroll
    for (int off = 32; off; off >>= 1) {
      p1 += __shfl_xor(p1, off, 64);
      p2 += __shfl_xor(p2, off, 64);
    }
    if (lane == 0) {
      Ag[row]  = expf(p1);
      Apg[row] = expf(LRALPHA * p1);
      Tg[row]  = expf(-p1);
      Bv[row]  = expf(p2);
      Bpv[row] = expf(LRALPHA * p2);
    }
  }
  __syncthreads();

  // cvt + transposed store: lane = n within tile, wave picks channel subset
  const int b = row0 >> 12;
  const int n0 = row0 & (NN - 1);
#pragma unroll
  for (int cc = 0; cc < 16; ++cc) {
    int ch = cc * 4 + wave;
    float v = tile[lane][ch];          // stride 65: 2-way bank alias (free)
    short hi = f2bf(v);
    short lo = f2bf(v - bf2f(hi));     // h = hi + lo to ~2^-18
    size_t idx = ((size_t)(b * 64 + ch) << 12) + n0 + lane;
    hTh[idx] = (unsigned short)hi;
    hTl[idx] = (unsigned short)lo;
  }
}

// ---------- fused attention kernel ----------
// Block: 512 threads = 8 waves; 32 rows x 64 ch; waves split j 8 ways.
// __launch_bounds__(512, 4): VGPR cap 128 -> 4 waves/SIMD (round-6: +20 us).
// w single bf16; denominator via ones-B MFMA (numerator and denominator use
// IDENTICAL weights); h hi+lo bf16 pair (exact to 2^-18).
// B/Bp loads are software-pipelined one iteration ahead (rotating registers;
// Bv/Bpv carved with a 64-float pad so the last-iter prefetch is in-bounds).
__global__ __launch_bounds__(512, 4) void k_attn(
    const unsigned short* __restrict__ hTh, const unsigned short* __restrict__ hTl,
    const float* __restrict__ Ag, const float* __restrict__ Apg,
    const float* __restrict__ Tg,
    const float* __restrict__ Bv, const float* __restrict__ Bpv,
    float* __restrict__ out) {
  __shared__ float slab[4][32][65];
  __shared__ float l_lds[4][32];

  const int wave = threadIdx.x >> 6;   // 0..7
  const int lane = threadIdx.x & 63;
  const int m = lane & 15;             // A row within subtile / D col (channel)
  const int quad = lane >> 4;
  const int row0 = blockIdx.x * 32;    // 512 blocks
  const int b = row0 >> 12;
  const int i0 = row0 + m, i1 = row0 + 16 + m;

  const float Ar0 = Ag[i0], Ap0 = Apg[i0], T0 = Tg[i0];
  const float Ar1 = Ag[i1], Ap1 = Apg[i1], T1 = Tg[i1];

  f32x4 acc00 = {0,0,0,0}, acc01 = {0,0,0,0}, acc02 = {0,0,0,0}, acc03 = {0,0,0,0};
  f32x4 acc10 = {0,0,0,0}, acc11 = {0,0,0,0}, acc12 = {0,0,0,0}, acc13 = {0,0,0,0};
  f32x4 lacc0 = {0,0,0,0}, lacc1 = {0,0,0,0};

  bf16x8 ones;
#pragma unroll
  for (int e = 0; e < 8; ++e) ones[e] = (short)0x3F80;   // bf16 1.0

  const int j0 = wave * (NN / 8) + quad * 8;         // within batch
  const float4* Bq4  = (const float4*)(Bv  + (b << 12) + j0);
  const float4* Bpq4 = (const float4*)(Bpv + (b << 12) + j0);
  const unsigned short* hp = hTh + ((size_t)(b * 64 + m) << 12) + j0;
  const unsigned short* lp = hTl + ((size_t)(b * 64 + m) << 12) + j0;
  constexpr size_t CH16 = (size_t)16 << 12;          // 16-channel stride in hT
  constexpr int ITERS = NN / 8 / 32;                 // 16

  // prologue: load iteration 0's B/Bp
  float4 bA = Bq4[0], bB = Bq4[1];
  float4 pA = Bpq4[0], pB = Bpq4[1];

  for (int it = 0; it < ITERS; ++it) {
    // prefetch next iteration's B/Bp (pad makes the last one in-bounds)
    Bq4 += 8; Bpq4 += 8;
    float4 nbA = Bq4[0], nbB = Bq4[1];
    float4 npA = Bpq4[0], npB = Bpq4[1];

    bf16x8 hh0 = *(const bf16x8*)(hp);
    bf16x8 hh1 = *(const bf16x8*)(hp + CH16);
    bf16x8 hh2 = *(const bf16x8*)(hp + 2 * CH16);
    bf16x8 hh3 = *(const bf16x8*)(hp + 3 * CH16);
    bf16x8 hl0 = *(const bf16x8*)(lp);
    bf16x8 hl1 = *(const bf16x8*)(lp + CH16);
    bf16x8 hl2 = *(const bf16x8*)(lp + 2 * CH16);
    bf16x8 hl3 = *(const bf16x8*)(lp + 3 * CH16);

    float bvv[8] = {bA.x, bA.y, bA.z, bA.w, bB.x, bB.y, bB.z, bB.w};
    float pvv[8] = {pA.x, pA.y, pA.z, pA.w, pB.x, pB.y, pB.z, pB.w};

    float w0v[8], w1v[8];
#pragma unroll
    for (int e = 0; e < 8; ++e) {
      float Bj = bvv[e], Bpj = pvv[e];
      w0v[e] = (Bj >= T0) ? (Ar0 * Bj) : (Ap0 * Bpj);
      w1v[e] = (Bj >= T1) ? (Ar1 * Bj) : (Ap1 * Bpj);
    }
    union { bf16x8 v; unsigned int u[4]; } af0u, af1u;
#pragma unroll
    for (int p = 0; p < 4; ++p) {
      af0u.u[p] = packRNE(w0v[2 * p], w0v[2 * p + 1]);
      af1u.u[p] = packRNE(w1v[2 * p], w1v[2 * p + 1]);
    }
    bf16x8 af0 = af0u.v, af1 = af1u.v;

    lacc0 = __builtin_amdgcn_mfma_f32_16x16x32_bf16(af0, ones, lacc0, 0, 0, 0);
    lacc1 = __builtin_amdgcn_mfma_f32_16x16x32_bf16(af1, ones, lacc1, 0, 0, 0);
    acc00 = __builtin_amdgcn_mfma_f32_16x16x32_bf16(af0, hh0, acc00, 0, 0, 0);
    acc00 = __builtin_amdgcn_mfma_f32_16x16x32_bf16(af0, hl0, acc00, 0, 0, 0);
    acc01 = __builtin_amdgcn_mfma_f32_16x16x32_bf16(af0, hh1, acc01, 0, 0, 0);
    acc01 = __builtin_amdgcn_mfma_f32_16x16x32_bf16(af0, hl1, acc01, 0, 0, 0);
    acc02 = __builtin_amdgcn_mfma_f32_16x16x32_bf16(af0, hh2, acc02, 0, 0, 0);
    acc02 = __builtin_amdgcn_mfma_f32_16x16x32_bf16(af0, hl2, acc02, 0, 0, 0);
    acc03 = __builtin_amdgcn_mfma_f32_16x16x32_bf16(af0, hh3, acc03, 0, 0, 0);
    acc03 = __builtin_amdgcn_mfma_f32_16x16x32_bf16(af0, hl3, acc03, 0, 0, 0);
    acc10 = __builtin_amdgcn_mfma_f32_16x16x32_bf16(af1, hh0, acc10, 0, 0, 0);
    acc10 = __builtin_amdgcn_mfma_f32_16x16x32_bf16(af1, hl0, acc10, 0, 0, 0);
    acc11 = __builtin_amdgcn_mfma_f32_16x16x32_bf16(af1, hh1, acc11, 0, 0, 0);
    acc11 = __builtin_amdgcn_mfma_f32_16x16x32_bf16(af1, hl1, acc11, 0, 0, 0);
    acc12 = __builtin_amdgcn_mfma_f32_16x16x32_bf16(af1, hh2, acc12, 0, 0, 0);
    acc12 = __builtin_amdgcn_mfma_f32_16x16x32_bf16(af1, hl2, acc12, 0, 0, 0);
    acc13 = __builtin_amdgcn_mfma_f32_16x16x32_bf16(af1, hh3, acc13, 0, 0, 0);
    acc13 = __builtin_amdgcn_mfma_f32_16x16x32_bf16(af1, hl3, acc13, 0, 0, 0);

    hp += 32; lp += 32;
    bA = nbA; bB = nbB; pA = npA; pB = npB;
  }

  // two-stage cross-wave combine (waves 0-3 write, then waves 4-7 add)
  const int sidx = wave & 3;
  if (wave < 4) {
#pragma unroll
    for (int reg = 0; reg < 4; ++reg) {
      int rl = quad * 4 + reg;
      slab[sidx][rl][m]      = acc00[reg];
      slab[sidx][rl][m + 16] = acc01[reg];
      slab[sidx][rl][m + 32] = acc02[reg];
      slab[sidx][rl][m + 48] = acc03[reg];
      slab[sidx][16 + rl][m]      = acc10[reg];
      slab[sidx][16 + rl][m + 16] = acc11[reg];
      slab[sidx][16 + rl][m + 32] = acc12[reg];
      slab[sidx][16 + rl][m + 48] = acc13[reg];
    }
    if (m == 0) {
#pragma unroll
      for (int reg = 0; reg < 4; ++reg) {
        l_lds[sidx][quad * 4 + reg]      = lacc0[reg];
        l_lds[sidx][16 + quad * 4 + reg] = lacc1[reg];
      }
    }
  }
  __syncthreads();
  if (wave >= 4) {
#pragma unroll
    for (int reg = 0; reg < 4; ++reg) {
      int rl = quad * 4 + reg;
      slab[sidx][rl][m]      += acc00[reg];
      slab[sidx][rl][m + 16] += acc01[reg];
      slab[sidx][rl][m + 32] += acc02[reg];
      slab[sidx][rl][m + 48] += acc03[reg];
      slab[sidx][16 + rl][m]      += acc10[reg];
      slab[sidx][16 + rl][m + 16] += acc11[reg];
      slab[sidx][16 + rl][m + 32] += acc12[reg];
      slab[sidx][16 + rl][m + 48] += acc13[reg];
    }
    if (m == 0) {
#pragma unroll
      for (int reg = 0; reg < 4; ++reg) {
        l_lds[sidx][quad * 4 + reg]      += lacc0[reg];
        l_lds[sidx][16 + quad * 4 + reg] += lacc1[reg];
      }
    }
  }
  __syncthreads();

  // combine + normalize + store (each thread: 4 output elements)
#pragma unroll
  for (int k = 0; k < 4; ++k) {
    int f = threadIdx.x + 512 * k;      // 0..2047
    int rl = f >> 6, c = f & 63;
    float s = slab[0][rl][c] + slab[1][rl][c] + slab[2][rl][c] + slab[3][rl][c];
    float L = l_lds[0][rl] + l_lds[1][rl] + l_lds[2][rl] + l_lds[3][rl];
    out[((size_t)(row0 + rl)) * 64 + c] = s / L;
  }
}

// ---------- launcher ----------

extern "C" void kernel_launch(void* const* d_in, const int* in_sizes, int n_in,
                              void* d_out, int out_size, void* d_ws, size_t ws_size,
                              hipStream_t stream) {
  const float* feat = (const float*)d_in[0];
  // d_in[1] = adj : UNUSED by the reference computation
  const float* W = (const float*)d_in[2];
  const float* a = (const float*)d_in[3];
  float* out = (float*)d_out;

  char* ws = (char*)d_ws;
  size_t off = 0;
  auto carve = [&](size_t bytes) -> char* {
    char* p = ws + off;
    off = (off + bytes + 255) & ~(size_t)255;
    return p;
  };
  unsigned short* hTh = (unsigned short*)carve((size_t)ROWS * 64 * sizeof(unsigned short)); // 2 MB
  unsigned short* hTl = (unsigned short*)carve((size_t)ROWS * 64 * sizeof(unsigned short)); // 2 MB
  float* Ag    = (float*)carve(ROWS * sizeof(float));
  float* Apg   = (float*)carve(ROWS * sizeof(float));
  float* Tg    = (float*)carve(ROWS * sizeof(float));
  float* Bv    = (float*)carve((ROWS + 64) * sizeof(float));   // +64 pad: prefetch OOB-safe
  float* Bpv   = (float*)carve((ROWS + 64) * sizeof(float));   // +64 pad

  k_hcvt<<<ROWS / 64, 256, 0, stream>>>(feat, W, a, hTh, hTl, Ag, Apg, Tg, Bv, Bpv);
  k_attn<<<ROWS / 32, 512, 0, stream>>>(hTh, hTl, Ag, Apg, Tg, Bv, Bpv, out);
}

// Round 8
// 353.852 us; speedup vs baseline: 1.1745x; 1.1053x over previous
//
#include <hip/hip_runtime.h>
#include <hip/hip_bf16.h>
#include <cmath>

#define LRALPHA 0.2f

namespace {
constexpr int BB = 4;
constexpr int NN = 4096;
constexpr int ROWS = BB * NN;   // 16384
}

typedef __attribute__((ext_vector_type(8))) short bf16x8;
typedef __attribute__((ext_vector_type(4))) float f32x4;

static __device__ inline short f2bf(float x) {
  __hip_bfloat16 t = __float2bfloat16(x);
  return *reinterpret_cast<short*>(&t);
}
static __device__ inline float bf2f(short x) {
  __hip_bfloat16 t = *reinterpret_cast<__hip_bfloat16*>(&x);
  return __bfloat162float(t);
}
// packed RNE fp32->bf16 for two POSITIVE FINITE values (no NaN guard needed):
// elem0 = low 16 bits, elem1 = high 16 bits
static __device__ inline unsigned int packRNE(float a, float b) {
  unsigned int ua = __float_as_uint(a), ub = __float_as_uint(b);
  unsigned int ra = ua + 0x7FFFu + ((ua >> 16) & 1u);
  unsigned int rb = ub + 0x7FFFu + ((ub >> 16) & 1u);
  return (ra >> 16) | (rb & 0xFFFF0000u);
}

// ---------- fused h + prep kernel ----------
// 64 rows/block, 256 threads. Lane caches W[:,lane] in 64 VGPRs. h staged in
// LDS -> hi/lo bf16 stored in MFMA-B-coalesced layout:
//   hI[b][j>>3][ch][j&7]  (flat: (b<<18) + ((j>>3)<<9) + (ch<<3) + (j&7))
// so k_attn's B-fragment loads are dense 256-B-per-quad streams instead of
// 16-way cache-line gathers (round-7 lesson: hT[ch][n] made every load a
// 16-row scatter). Per row also computes s1 = h.a1, s2 = h.a2 and the
// exp-precomputes (no max-shift; unit-variance scores keep everything in
// fp32 range; the shift cancels in the ratio):
//   A = e^{s1}, A' = e^{0.2 s1}, B = e^{s2}, B' = e^{0.2 s2}
// Hot-loop weight: w_ij = max(A_i*B_j, A'_i*B'_j)   [= lrelu-softmax weight,
// since e^t >= e^{0.2t} iff t >= 0 -- no threshold compare needed]
__global__ __launch_bounds__(256) void k_hcvt(
    const float* __restrict__ feat, const float* __restrict__ W,
    const float* __restrict__ a,
    unsigned short* __restrict__ hTh, unsigned short* __restrict__ hTl,
    float* __restrict__ Ag, float* __restrict__ Apg,
    float* __restrict__ Bv, float* __restrict__ Bpv) {
  __shared__ float tile[64][65];
  const int lane = threadIdx.x & 63;
  const int wave = threadIdx.x >> 6;
  const int row0 = blockIdx.x * 64;    // 256 blocks; never straddles a batch

  float wreg[64];
#pragma unroll
  for (int k = 0; k < 64; ++k) wreg[k] = W[k * 64 + lane];  // coalesced, once
  const float a1 = a[lane], a2 = a[64 + lane];

  for (int r = 0; r < 16; ++r) {
    const int row = row0 + wave * 16 + r;
    const float4* f4 = (const float4*)(feat + (size_t)row * 64);  // wave-uniform
    float hv = 0.f;
#pragma unroll
    for (int kk = 0; kk < 16; ++kk) {
      float4 f = f4[kk];
      hv = fmaf(f.x, wreg[4 * kk + 0], hv);
      hv = fmaf(f.y, wreg[4 * kk + 1], hv);
      hv = fmaf(f.z, wreg[4 * kk + 2], hv);
      hv = fmaf(f.w, wreg[4 * kk + 3], hv);
    }
    tile[wave * 16 + r][lane] = hv;
    float p1 = hv * a1, p2 = hv * a2;
#pragma unroll
    for (int off = 32; off; off >>= 1) {
      p1 += __shfl_xor(p1, off, 64);
      p2 += __shfl_xor(p2, off, 64);
    }
    if (lane == 0) {
      Ag[row]  = expf(p1);
      Apg[row] = expf(LRALPHA * p1);
      Bv[row]  = expf(p2);
      Bpv[row] = expf(LRALPHA * p2);
    }
  }
  __syncthreads();

  // cvt + interleaved store: lane = n within 64-row tile, wave picks channels
  const int b = row0 >> 12;
  const int n0 = row0 & (NN - 1);      // multiple of 64
  const size_t base = ((size_t)b << 18) + ((size_t)(n0 >> 3) << 9)
                    + ((size_t)(lane >> 3) << 9) + (lane & 7);
#pragma unroll
  for (int cc = 0; cc < 16; ++cc) {
    int ch = cc * 4 + wave;
    float v = tile[lane][ch];          // stride 65: 2-way bank alias (free)
    short hi = f2bf(v);
    short lo = f2bf(v - bf2f(hi));     // h = hi + lo to ~2^-18
    size_t idx = base + (ch << 3);
    hTh[idx] = (unsigned short)hi;
    hTl[idx] = (unsigned short)lo;
  }
}

// ---------- fused attention kernel ----------
// Block: 512 threads = 8 waves; 32 rows x 64 ch; waves split j 8 ways.
// __launch_bounds__(512, 4): VGPR cap 128 -> 4 waves/SIMD (round-6: +20 us).
// w single bf16 via max-form; denominator via ones-B MFMA (numerator and
// denominator use IDENTICAL weights); h hi+lo bf16 pair (exact to 2^-18).
// h loads now stream dense 1-KB blocks per quad (hI layout).
__global__ __launch_bounds__(512, 4) void k_attn(
    const unsigned short* __restrict__ hTh, const unsigned short* __restrict__ hTl,
    const float* __restrict__ Ag, const float* __restrict__ Apg,
    const float* __restrict__ Bv, const float* __restrict__ Bpv,
    float* __restrict__ out) {
  __shared__ float slab[4][32][65];
  __shared__ float l_lds[4][32];

  const int wave = threadIdx.x >> 6;   // 0..7
  const int lane = threadIdx.x & 63;
  const int m = lane & 15;             // A row within subtile / D col (channel)
  const int quad = lane >> 4;
  const int row0 = blockIdx.x * 32;    // 512 blocks
  const int b = row0 >> 12;
  const int i0 = row0 + m, i1 = row0 + 16 + m;

  const float Ar0 = Ag[i0], Ap0 = Apg[i0];
  const float Ar1 = Ag[i1], Ap1 = Apg[i1];

  f32x4 acc00 = {0,0,0,0}, acc01 = {0,0,0,0}, acc02 = {0,0,0,0}, acc03 = {0,0,0,0};
  f32x4 acc10 = {0,0,0,0}, acc11 = {0,0,0,0}, acc12 = {0,0,0,0}, acc13 = {0,0,0,0};
  f32x4 lacc0 = {0,0,0,0}, lacc1 = {0,0,0,0};

  bf16x8 ones;
#pragma unroll
  for (int e = 0; e < 8; ++e) ones[e] = (short)0x3F80;   // bf16 1.0

  const int j0 = wave * (NN / 8) + quad * 8;         // within batch
  const float4* Bq4  = (const float4*)(Bv  + (b << 12) + j0);
  const float4* Bpq4 = (const float4*)(Bpv + (b << 12) + j0);
  // hI layout: element (j, ch) at (b<<18) + ((j>>3)<<9) + (ch<<3) + (j&7).
  // This lane's 8 j are j0+it*32 .. +7  ->  block (j0>>3)+it*4 (+quad folded in)
  const unsigned short* hp = hTh + ((size_t)b << 18)
                           + ((size_t)(j0 >> 3) << 9) + (m << 3);
  const unsigned short* lp = hTl + ((size_t)b << 18)
                           + ((size_t)(j0 >> 3) << 9) + (m << 3);
  constexpr int ITERS = NN / 8 / 32;                 // 16

  // prologue: load iteration 0's B/Bp
  float4 bA = Bq4[0], bB = Bq4[1];
  float4 pA = Bpq4[0], pB = Bpq4[1];

  for (int it = 0; it < ITERS; ++it) {
    // prefetch next iteration's B/Bp (pad makes the last one in-bounds)
    Bq4 += 8; Bpq4 += 8;
    float4 nbA = Bq4[0], nbB = Bq4[1];
    float4 npA = Bpq4[0], npB = Bpq4[1];

    bf16x8 hh0 = *(const bf16x8*)(hp);         // ch group m
    bf16x8 hh1 = *(const bf16x8*)(hp + 128);   // ch group m+16
    bf16x8 hh2 = *(const bf16x8*)(hp + 256);   // ch group m+32
    bf16x8 hh3 = *(const bf16x8*)(hp + 384);   // ch group m+48
    bf16x8 hl0 = *(const bf16x8*)(lp);
    bf16x8 hl1 = *(const bf16x8*)(lp + 128);
    bf16x8 hl2 = *(const bf16x8*)(lp + 256);
    bf16x8 hl3 = *(const bf16x8*)(lp + 384);

    float bvv[8] = {bA.x, bA.y, bA.z, bA.w, bB.x, bB.y, bB.z, bB.w};
    float pvv[8] = {pA.x, pA.y, pA.z, pA.w, pB.x, pB.y, pB.z, pB.w};

    float w0v[8], w1v[8];
#pragma unroll
    for (int e = 0; e < 8; ++e) {
      float Bj = bvv[e], Bpj = pvv[e];
      w0v[e] = fmaxf(Ar0 * Bj, Ap0 * Bpj);   // = lrelu-softmax weight
      w1v[e] = fmaxf(Ar1 * Bj, Ap1 * Bpj);
    }
    union { bf16x8 v; unsigned int u[4]; } af0u, af1u;
#pragma unroll
    for (int p = 0; p < 4; ++p) {
      af0u.u[p] = packRNE(w0v[2 * p], w0v[2 * p + 1]);
      af1u.u[p] = packRNE(w1v[2 * p], w1v[2 * p + 1]);
    }
    bf16x8 af0 = af0u.v, af1 = af1u.v;

    lacc0 = __builtin_amdgcn_mfma_f32_16x16x32_bf16(af0, ones, lacc0, 0, 0, 0);
    lacc1 = __builtin_amdgcn_mfma_f32_16x16x32_bf16(af1, ones, lacc1, 0, 0, 0);
    acc00 = __builtin_amdgcn_mfma_f32_16x16x32_bf16(af0, hh0, acc00, 0, 0, 0);
    acc00 = __builtin_amdgcn_mfma_f32_16x16x32_bf16(af0, hl0, acc00, 0, 0, 0);
    acc01 = __builtin_amdgcn_mfma_f32_16x16x32_bf16(af0, hh1, acc01, 0, 0, 0);
    acc01 = __builtin_amdgcn_mfma_f32_16x16x32_bf16(af0, hl1, acc01, 0, 0, 0);
    acc02 = __builtin_amdgcn_mfma_f32_16x16x32_bf16(af0, hh2, acc02, 0, 0, 0);
    acc02 = __builtin_amdgcn_mfma_f32_16x16x32_bf16(af0, hl2, acc02, 0, 0, 0);
    acc03 = __builtin_amdgcn_mfma_f32_16x16x32_bf16(af0, hh3, acc03, 0, 0, 0);
    acc03 = __builtin_amdgcn_mfma_f32_16x16x32_bf16(af0, hl3, acc03, 0, 0, 0);
    acc10 = __builtin_amdgcn_mfma_f32_16x16x32_bf16(af1, hh0, acc10, 0, 0, 0);
    acc10 = __builtin_amdgcn_mfma_f32_16x16x32_bf16(af1, hl0, acc10, 0, 0, 0);
    acc11 = __builtin_amdgcn_mfma_f32_16x16x32_bf16(af1, hh1, acc11, 0, 0, 0);
    acc11 = __builtin_amdgcn_mfma_f32_16x16x32_bf16(af1, hl1, acc11, 0, 0, 0);
    acc12 = __builtin_amdgcn_mfma_f32_16x16x32_bf16(af1, hh2, acc12, 0, 0, 0);
    acc12 = __builtin_amdgcn_mfma_f32_16x16x32_bf16(af1, hl2, acc12, 0, 0, 0);
    acc13 = __builtin_amdgcn_mfma_f32_16x16x32_bf16(af1, hh3, acc13, 0, 0, 0);
    acc13 = __builtin_amdgcn_mfma_f32_16x16x32_bf16(af1, hl3, acc13, 0, 0, 0);

    hp += 2048; lp += 2048;     // 4 j8-blocks of 512 elements per iter
    bA = nbA; bB = nbB; pA = npA; pB = npB;
  }

  // two-stage cross-wave combine (waves 0-3 write, then waves 4-7 add)
  const int sidx = wave & 3;
  if (wave < 4) {
#pragma unroll
    for (int reg = 0; reg < 4; ++reg) {
      int rl = quad * 4 + reg;
      slab[sidx][rl][m]      = acc00[reg];
      slab[sidx][rl][m + 16] = acc01[reg];
      slab[sidx][rl][m + 32] = acc02[reg];
      slab[sidx][rl][m + 48] = acc03[reg];
      slab[sidx][16 + rl][m]      = acc10[reg];
      slab[sidx][16 + rl][m + 16] = acc11[reg];
      slab[sidx][16 + rl][m + 32] = acc12[reg];
      slab[sidx][16 + rl][m + 48] = acc13[reg];
    }
    if (m == 0) {
#pragma unroll
      for (int reg = 0; reg < 4; ++reg) {
        l_lds[sidx][quad * 4 + reg]      = lacc0[reg];
        l_lds[sidx][16 + quad * 4 + reg] = lacc1[reg];
      }
    }
  }
  __syncthreads();
  if (wave >= 4) {
#pragma unroll
    for (int reg = 0; reg < 4; ++reg) {
      int rl = quad * 4 + reg;
      slab[sidx][rl][m]      += acc00[reg];
      slab[sidx][rl][m + 16] += acc01[reg];
      slab[sidx][rl][m + 32] += acc02[reg];
      slab[sidx][rl][m + 48] += acc03[reg];
      slab[sidx][16 + rl][m]      += acc10[reg];
      slab[sidx][16 + rl][m + 16] += acc11[reg];
      slab[sidx][16 + rl][m + 32] += acc12[reg];
      slab[sidx][16 + rl][m + 48] += acc13[reg];
    }
    if (m == 0) {
#pragma unroll
      for (int reg = 0; reg < 4; ++reg) {
        l_lds[sidx][quad * 4 + reg]      += lacc0[reg];
        l_lds[sidx][16 + quad * 4 + reg] += lacc1[reg];
      }
    }
  }
  __syncthreads();

  // combine + normalize + store (each thread: 4 output elements)
#pragma unroll
  for (int k = 0; k < 4; ++k) {
    int f = threadIdx.x + 512 * k;      // 0..2047
    int rl = f >> 6, c = f & 63;
    float s = slab[0][rl][c] + slab[1][rl][c] + slab[2][rl][c] + slab[3][rl][c];
    float L = l_lds[0][rl] + l_lds[1][rl] + l_lds[2][rl] + l_lds[3][rl];
    out[((size_t)(row0 + rl)) * 64 + c] = s / L;
  }
}

// ---------- launcher ----------

extern "C" void kernel_launch(void* const* d_in, const int* in_sizes, int n_in,
                              void* d_out, int out_size, void* d_ws, size_t ws_size,
                              hipStream_t stream) {
  const float* feat = (const float*)d_in[0];
  // d_in[1] = adj : UNUSED by the reference computation
  const float* W = (const float*)d_in[2];
  const float* a = (const float*)d_in[3];
  float* out = (float*)d_out;

  char* ws = (char*)d_ws;
  size_t off = 0;
  auto carve = [&](size_t bytes) -> char* {
    char* p = ws + off;
    off = (off + bytes + 255) & ~(size_t)255;
    return p;
  };
  unsigned short* hTh = (unsigned short*)carve((size_t)ROWS * 64 * sizeof(unsigned short)); // 2 MB
  unsigned short* hTl = (unsigned short*)carve((size_t)ROWS * 64 * sizeof(unsigned short)); // 2 MB
  float* Ag    = (float*)carve(ROWS * sizeof(float));
  float* Apg   = (float*)carve(ROWS * sizeof(float));
  float* Bv    = (float*)carve((ROWS + 64) * sizeof(float));   // +64 pad: prefetch OOB-safe
  float* Bpv   = (float*)carve((ROWS + 64) * sizeof(float));   // +64 pad

  k_hcvt<<<ROWS / 64, 256, 0, stream>>>(feat, W, a, hTh, hTl, Ag, Apg, Bv, Bpv);
  k_attn<<<ROWS / 32, 512, 0, stream>>>(hTh, hTl, Ag, Apg, Bv, Bpv, out);
}